// Round 17
// baseline (155.123 us; speedup 1.0000x reference)
//
#include <hip/hip_runtime.h>
#include <math.h>

typedef short bf16x8 __attribute__((ext_vector_type(8)));
typedef float f32x4  __attribute__((ext_vector_type(4)));

#define N_SMPS 16384
#define N_FCNS 2048
#define D_IN 32
#define D_OUT 32
#define KNN 4
#define SPLITS 4
#define CPS 512            // centers per split (one wave per split)
#define TILES 32           // CPS / 16
#define POOL 48            // 8 subsets x top-6, all-distinct candidates
#define SMP 16
#define NPAIR (N_SMPS * KNN)

__device__ __forceinline__ unsigned umin_u(unsigned a, unsigned b) { return a < b ? a : b; }
__device__ __forceinline__ unsigned umax_u(unsigned a, unsigned b) { return a > b ? a : b; }

__device__ __forceinline__ unsigned short bf16_rne(float f) {
  unsigned b = __float_as_uint(f);
  unsigned r = b + 0x7FFFu + ((b >> 16) & 1u);
  return (unsigned short)(r >> 16);
}

// ---------------- ws layout (bytes) ------------------------------------------
#define OFF_XH   0u
#define OFF_CH   1048576u
#define OFF_HB   1179648u
#define OFF_WB   1187840u
#define OFF_POOL 5382144u
#define OFF_IDX  8527872u
#define OFF_CNT  8790016u
#define OFF_CNT2 8798208u
#define OFF_BASE 8806400u
#define OFF_LIST 8814848u
#define OFF_PART 9076992u   // 8 MB -> total ~17.5 MB

#define NX4 (N_SMPS * D_IN / 4)            // 131072
#define NC4 (N_FCNS * D_IN / 4)            // 16384
#define NW4 (N_FCNS * D_IN * D_OUT / 4)    // 524288
#define NTOT (NX4 + NC4 + NW4)             // 671744 = 2624 * 256

// ---------------- Kernel 0: bf16 conversion + norms + counter zeroing --------
__global__ __launch_bounds__(256) void k_prep(
    const float* __restrict__ x, const float* __restrict__ ctrs,
    const float* __restrict__ wts,
    unsigned short* __restrict__ xh, unsigned short* __restrict__ ch,
    unsigned short* __restrict__ wb, float* __restrict__ hb,
    int* __restrict__ cnt, int* __restrict__ cnt2)
{
  const int gt = blockIdx.x * 256 + threadIdx.x;
  const float* src; unsigned short* dst; int i4;
  if (gt < NX4)            { src = x;    dst = xh; i4 = gt; }
  else if (gt < NX4 + NC4) { src = ctrs; dst = ch; i4 = gt - NX4; }
  else                     { src = wts;  dst = wb; i4 = gt - (NX4 + NC4); }
  float4 v = ((const float4*)src)[i4];
  ushort4 o;
  o.x = bf16_rne(v.x); o.y = bf16_rne(v.y);
  o.z = bf16_rne(v.z); o.w = bf16_rne(v.w);
  ((ushort4*)dst)[i4] = o;

  if (gt < N_FCNS) {   // fp32-exact half-norms + zero bucket counters
    const float4* cp4 = (const float4*)(ctrs + (size_t)gt * D_IN);
    float a = 0.f;
    #pragma unroll
    for (int q = 0; q < 8; ++q) {
      float4 c = cp4[q];
      a += c.x * c.x + c.y * c.y + c.z * c.z + c.w * c.w;
    }
    hb[gt] = -0.5f * a;
    cnt[gt] = 0;
    cnt2[gt] = 0;
  }
}

// ---------------- Kernel 1: MFMA topk -> 48-key pool (R16 phase-1 verbatim) --
__global__ __launch_bounds__(256) void k_topk(
    const unsigned short* __restrict__ xh, const unsigned short* __restrict__ ch,
    const float* __restrict__ hb, unsigned* __restrict__ pool)
{
  __shared__ unsigned s_cand[SPLITS][16][16][4];   // 16 KB
  __shared__ float    s_hb[SPLITS * CPS];          // 8 KB

  const int tid = threadIdx.x;
  const int lane = tid & 63;
  const int w = __builtin_amdgcn_readfirstlane(tid >> 6);  // wave = split
  const int col = lane & 15;
  const int quad = lane >> 4;
  const int sbase = blockIdx.x * SMP;
  const int nbase0 = w * CPS;

  #pragma unroll
  for (int r = 0; r < CPS / 64; ++r)
    s_hb[nbase0 + r * 64 + lane] = hb[nbase0 + r * 64 + lane];

  const bf16x8 ah =
      *(const bf16x8*)(xh + (size_t)(sbase + col) * D_IN + quad * 8);

  unsigned ls[4][4];
  #pragma unroll
  for (int r = 0; r < 4; ++r)
    #pragma unroll
    for (int e = 0; e < 4; ++e) ls[r][e] = 0u;   // real keys always > 0

  const unsigned short* chb =
      ch + (size_t)nbase0 * D_IN + (size_t)col * D_IN + quad * 8;
  #define BLOAD(t) (*(const bf16x8*)(chb + (size_t)(t) * 16 * D_IN))
  #define HLOAD(t) (s_hb[nbase0 + (t) * 16 + col])

  __syncthreads();

  bf16x8 bh[4];
  float  hv[4];
  #pragma unroll
  for (int p = 0; p < 4; ++p) { bh[p] = BLOAD(p); hv[p] = HLOAD(p); }

  for (int t = 0; t < TILES; t += 4) {
    #pragma unroll
    for (int p = 0; p < 4; ++p) {
      {
        f32x4 acc = {0.f, 0.f, 0.f, 0.f};
        acc = __builtin_amdgcn_mfma_f32_16x16x32_bf16(ah, bh[p], acc, 0, 0, 0);
        const unsigned tc = (unsigned)((t + p) * 16 + col);
        const float hvv = hv[p];
        #pragma unroll
        for (int r = 0; r < 4; ++r) {
          const float uu = acc[r] + hvv;
          unsigned b = __float_as_uint(uu);
          unsigned m = b ^ ((unsigned)((int)b >> 31) | 0x80000000u);
          unsigned key = (m & 0xFFFFFE00u) | tc;
          unsigned t0 = umin_u(ls[r][0], key); ls[r][0] = umax_u(ls[r][0], key);
          unsigned t1 = umin_u(ls[r][1], t0);  ls[r][1] = umax_u(ls[r][1], t0);
          unsigned t2 = umin_u(ls[r][2], t1);  ls[r][2] = umax_u(ls[r][2], t1);
          ls[r][3] = umax_u(ls[r][3], t2);
        }
      }
      const int tn = (t + 4 + p) & (TILES - 1);
      bh[p] = BLOAD(tn);
      hv[p] = HLOAD(tn);
    }
  }
  #undef BLOAD
  #undef HLOAD

  #pragma unroll
  for (int r = 0; r < 4; ++r) {
    const int row = quad * 4 + r;
    *(uint4*)&s_cand[w][row][col][0] =
        make_uint4(ls[r][0], ls[r][1], ls[r][2], ls[r][3]);
  }
  __syncthreads();

  if (tid < 128) {
    const int sl = tid >> 3;
    const int g  = tid & 7;
    const int wv = g >> 1;
    const int chh = (g & 1) * 8;
    unsigned q0 = 0, q1 = 0, q2 = 0, q3 = 0, q4 = 0, q5 = 0;
    #pragma unroll
    for (int c2 = 0; c2 < 8; ++c2) {
      uint4 kv = *(const uint4*)&s_cand[wv][sl][chh + c2][0];
      unsigned ks[4] = {kv.x, kv.y, kv.z, kv.w};
      #pragma unroll
      for (int e = 0; e < 4; ++e) {
        unsigned key = ks[e];
        unsigned t0 = umin_u(q0, key); q0 = umax_u(q0, key);
        unsigned t1 = umin_u(q1, t0);  q1 = umax_u(q1, t0);
        unsigned t2 = umin_u(q2, t1);  q2 = umax_u(q2, t1);
        unsigned t3 = umin_u(q3, t2);  q3 = umax_u(q3, t2);
        unsigned t4 = umin_u(q4, t3);  q4 = umax_u(q4, t3);
        q5 = umax_u(q5, t4);
      }
    }
    unsigned* op = pool + (size_t)(sbase + sl) * POOL + g * 6;
    op[0] = q0; op[1] = q1; op[2] = q2;
    op[3] = q3; op[4] = q4; op[5] = q5;
  }
}

// ---------------- Kernel 2: fp64 refine (proven) + bucket histogram ----------
__global__ __launch_bounds__(256) void k_refine(
    const float* __restrict__ x, const float* __restrict__ ctrs,
    const unsigned* __restrict__ pool, int* __restrict__ idx_out,
    int* __restrict__ cnt)
{
  __shared__ double s_pd2[SMP][POOL];
  __shared__ int    s_pix[SMP][POOL];
  const int tid = threadIdx.x;
  const int sbase = blockIdx.x * SMP;

  for (int c = tid; c < SMP * POOL; c += 256) {
    const int sl = c / POOL;
    const int p = c - sl * POOL;
    const unsigned key = pool[(size_t)(sbase + sl) * POOL + p];
    const int wv = p / 12;
    const int j = wv * CPS + (int)(key & 0x1FFu);
    const float4* xp4 = (const float4*)(x + (size_t)(sbase + sl) * D_IN);
    const float4* cp4 = (const float4*)(ctrs + (size_t)j * D_IN);
    double d2a = 0.0, d2b = 0.0;
    #pragma unroll
    for (int q = 0; q < 8; ++q) {
      float4 cv = cp4[q];
      float4 xv = xp4[q];
      double df0 = (double)xv.x - (double)cv.x;
      double df1 = (double)xv.y - (double)cv.y;
      double df2 = (double)xv.z - (double)cv.z;
      double df3 = (double)xv.w - (double)cv.w;
      d2a = fma(df0, df0, d2a);
      d2b = fma(df1, df1, d2b);
      d2a = fma(df2, df2, d2a);
      d2b = fma(df3, df3, d2b);
    }
    s_pd2[sl][p] = d2a + d2b;
    s_pix[sl][p] = j;
  }
  __syncthreads();

  if (tid < SMP) {
    double bd[4]; int b4[4];
    #pragma unroll
    for (int e = 0; e < 4; ++e) { bd[e] = 1e300; b4[e] = 0x7fffffff; }
    for (int m = 0; m < POOL; ++m) {
      const double d2 = s_pd2[tid][m];
      const int j = s_pix[tid][m];
      bool ins = (d2 < bd[3]) || (d2 == bd[3] && j < b4[3]);
      if (ins) {
        bd[3] = d2; b4[3] = j;
        #pragma unroll
        for (int q = 3; q > 0; --q) {
          bool sw = (bd[q] < bd[q - 1]) ||
                    (bd[q] == bd[q - 1] && b4[q] < b4[q - 1]);
          if (sw) {
            double td = bd[q]; bd[q] = bd[q - 1]; bd[q - 1] = td;
            int    tj = b4[q]; b4[q] = b4[q - 1]; b4[q - 1] = tj;
          }
        }
      }
    }
    #pragma unroll
    for (int q = 0; q < 4; ++q) {
      idx_out[(sbase + tid) * KNN + q] = b4[q];
      atomicAdd(&cnt[b4[q]], 1);
    }
  }
}

// ---------------- Kernel 3: exclusive prefix over 2048 counts (R8 proven) ----
__global__ __launch_bounds__(256) void k_scan(
    const int* __restrict__ cnt, int* __restrict__ base)
{
  __shared__ int s_sum[256];
  const int tid = threadIdx.x;
  int loc[8]; int acc = 0;
  #pragma unroll
  for (int q = 0; q < 8; ++q) { loc[q] = acc; acc += cnt[tid * 8 + q]; }
  s_sum[tid] = acc;
  __syncthreads();
  #pragma unroll
  for (int off = 1; off < 256; off <<= 1) {
    int v = (tid >= off) ? s_sum[tid - off] : 0;
    __syncthreads();
    s_sum[tid] += v;
    __syncthreads();
  }
  const int pre = (tid == 0) ? 0 : s_sum[tid - 1];
  #pragma unroll
  for (int q = 0; q < 8; ++q) base[tid * 8 + q] = pre + loc[q];
  if (tid == 255) base[N_FCNS] = pre + acc;   // = NPAIR
}

// ---------------- Kernel 4: place pairs into dense f-sorted list (R8) --------
__global__ __launch_bounds__(256) void k_place(
    const int* __restrict__ idx, const int* __restrict__ base,
    int* __restrict__ cnt2, int* __restrict__ list)
{
  const int t = blockIdx.x * 256 + threadIdx.x;   // t = s*4 + j
  const int f = idx[t];
  const int pos = base[f] + atomicAdd(&cnt2[f], 1);
  list[pos] = t;                                   // dense, no cap
}

// ---------------- Kernel 5: sorted-gather apply (uniform 64-pair chunks) -----
// Chunks of the f-sorted list: adjacent pairs share centers -> W rows hit
// L1/L2 with ~30x reuse (134 MB gather -> ~8 MB). Per-pair FMA order and
// part[sv] indexing identical to R16 phase 5 -> bitwise-identical y.
__global__ __launch_bounds__(256) void k_apply2(
    const float* __restrict__ x, const float* __restrict__ ctrs,
    const unsigned short* __restrict__ wb, const float* __restrict__ offs,
    const int* __restrict__ idx, const int* __restrict__ list,
    float* __restrict__ part)
{
  __shared__ float s_diff[64][D_IN + 1];   // 8.25 KB
  __shared__ int   s_t[64];
  __shared__ int   s_f[64];
  const int tid = threadIdx.x;
  const int pbase = blockIdx.x * 64;

  if (tid < 64) {
    const int t = list[pbase + tid];
    s_t[tid] = t;
    s_f[tid] = idx[t];
  }
  __syncthreads();

  // stage diffs: pair i = tid>>2, segment seg = tid&3 (8 floats)
  {
    const int i = tid >> 2, seg = tid & 3;
    const int s = s_t[i] >> 2, f = s_f[i];
    const float4* xp = (const float4*)(x + (size_t)s * D_IN) + seg * 2;
    const float4* cp = (const float4*)(ctrs + (size_t)f * D_IN) + seg * 2;
    float4 xv0 = xp[0], xv1 = xp[1], cv0 = cp[0], cv1 = cp[1];
    float* dp = &s_diff[i][seg * 8];
    dp[0] = xv0.x - cv0.x; dp[1] = xv0.y - cv0.y;
    dp[2] = xv0.z - cv0.z; dp[3] = xv0.w - cv0.w;
    dp[4] = xv1.x - cv1.x; dp[5] = xv1.y - cv1.y;
    dp[6] = xv1.z - cv1.z; dp[7] = xv1.w - cv1.w;
  }
  __syncthreads();

  #pragma unroll
  for (int r = 0; r < 2; ++r) {
    const int task = r * 256 + tid;
    const int pr = task >> 3;
    const int eq = task & 7;
    const int f = s_f[pr];
    const uint2* wp = (const uint2*)(wb + (size_t)f * (D_IN * D_OUT));
    float4 acc = ((const float4*)(offs + (size_t)f * D_OUT))[eq];
    #pragma unroll
    for (int d = 0; d < D_IN; ++d) {
      uint2 wv = wp[d * 8 + eq];
      float w0 = __uint_as_float(wv.x << 16);
      float w1 = __uint_as_float(wv.x & 0xFFFF0000u);
      float w2 = __uint_as_float(wv.y << 16);
      float w3 = __uint_as_float(wv.y & 0xFFFF0000u);
      float xc = s_diff[pr][d];
      acc.x = fmaf(xc, w0, acc.x);
      acc.y = fmaf(xc, w1, acc.y);
      acc.z = fmaf(xc, w2, acc.z);
      acc.w = fmaf(xc, w3, acc.w);
    }
    ((float4*)(part + (size_t)s_t[pr] * D_OUT))[eq] = acc;
  }
}

// ---------------- Kernel 6: reduce 4 partials per sample (R8 proven) ---------
__global__ __launch_bounds__(256) void k_reduce(
    const float* __restrict__ part, float* __restrict__ y)
{
  const int t = blockIdx.x * 256 + threadIdx.x;   // t = s*8 + c4
  const int s = t >> 3;
  const int c4 = t & 7;
  const float4* p = (const float4*)(part + (size_t)s * 4 * D_OUT) + c4;
  float4 a = p[0], b = p[8], c = p[16], e = p[24];
  float4 o;
  o.x = (a.x + b.x) + (c.x + e.x);
  o.y = (a.y + b.y) + (c.y + e.y);
  o.z = (a.z + b.z) + (c.z + e.z);
  o.w = (a.w + b.w) + (c.w + e.w);
  ((float4*)(y + (size_t)s * D_OUT))[c4] = o;
}

// ---------------- launch: 7 dispatches (graph replay: ~1 us each) ------------
extern "C" void kernel_launch(void* const* d_in, const int* in_sizes, int n_in,
                              void* d_out, int out_size, void* d_ws, size_t ws_size,
                              hipStream_t stream) {
  const float* x    = (const float*)d_in[0];
  const float* ctrs = (const float*)d_in[1];
  const float* wts  = (const float*)d_in[2];
  const float* offs = (const float*)d_in[3];
  float* y = (float*)d_out;

  char* ws = (char*)d_ws;
  unsigned short* xh = (unsigned short*)(ws + OFF_XH);
  unsigned short* ch = (unsigned short*)(ws + OFF_CH);
  float*          hb = (float*)(ws + OFF_HB);
  unsigned short* wb = (unsigned short*)(ws + OFF_WB);
  unsigned*     pool = (unsigned*)(ws + OFF_POOL);
  int*          idxb = (int*)(ws + OFF_IDX);
  int*           cnt = (int*)(ws + OFF_CNT);
  int*          cnt2 = (int*)(ws + OFF_CNT2);
  int*          base = (int*)(ws + OFF_BASE);
  int*          list = (int*)(ws + OFF_LIST);
  float*        part = (float*)(ws + OFF_PART);

  k_prep<<<NTOT / 256, 256, 0, stream>>>(x, ctrs, wts, xh, ch, wb, hb,
                                         cnt, cnt2);
  k_topk<<<N_SMPS / SMP, 256, 0, stream>>>(xh, ch, hb, pool);
  k_refine<<<N_SMPS / SMP, 256, 0, stream>>>(x, ctrs, pool, idxb, cnt);
  k_scan<<<1, 256, 0, stream>>>(cnt, base);
  k_place<<<NPAIR / 256, 256, 0, stream>>>(idxb, base, cnt2, list);
  k_apply2<<<NPAIR / 64, 256, 0, stream>>>(x, ctrs, wb, offs, idxb, list, part);
  k_reduce<<<(N_SMPS * 8) / 256, 256, 0, stream>>>(part, y);
}

// Round 18
// 115.768 us; speedup vs baseline: 1.3399x; 1.3399x over previous
//
#include <hip/hip_runtime.h>
#include <math.h>

typedef short bf16x8 __attribute__((ext_vector_type(8)));
typedef float f32x4  __attribute__((ext_vector_type(4)));

#define N_SMPS 16384
#define N_FCNS 2048
#define D_IN 32
#define D_OUT 32
#define KNN 4
#define SPLITS 4
#define CPS 512            // centers per split (one wave per split)
#define TILES 32           // CPS / 16
#define POOL 48            // 8 subsets x top-6, all-distinct candidates
#define SMP 16             // samples per block

__device__ __forceinline__ unsigned umin_u(unsigned a, unsigned b) { return a < b ? a : b; }
__device__ __forceinline__ unsigned umax_u(unsigned a, unsigned b) { return a > b ? a : b; }

// round-to-nearest-even fp32 -> bf16
__device__ __forceinline__ unsigned short bf16_rne(float f) {
  unsigned b = __float_as_uint(f);
  unsigned r = b + 0x7FFFu + ((b >> 16) & 1u);
  return (unsigned short)(r >> 16);
}

// ---------------- ws layout (bytes) ------------------------------------------
// xh 1MB | ch 128K | hb 8K | wb 4MB   -> ~5.2 MB
#define OFF_XH   0u
#define OFF_CH   1048576u
#define OFF_HB   (OFF_CH + 131072u)
#define OFF_WB   (OFF_HB + 8192u)

#define NX4 (N_SMPS * D_IN / 4)            // 131072
#define NC4 (N_FCNS * D_IN / 4)            // 16384
#define NW4 (N_FCNS * D_IN * D_OUT / 4)    // 524288
#define NTOT (NX4 + NC4 + NW4)             // 671744 = 2624 * 256

// ---------------- Kernel 0: bf16 RNE conversion (x, ctrs, W) + norms ---------
// (byte-identical to R16's passing k_prep)
__global__ __launch_bounds__(256) void k_prep(
    const float* __restrict__ x, const float* __restrict__ ctrs,
    const float* __restrict__ wts,
    unsigned short* __restrict__ xh, unsigned short* __restrict__ ch,
    unsigned short* __restrict__ wb, float* __restrict__ hb)
{
  const int gt = blockIdx.x * 256 + threadIdx.x;
  const float* src; unsigned short* dst; int i4;
  if (gt < NX4)            { src = x;    dst = xh; i4 = gt; }
  else if (gt < NX4 + NC4) { src = ctrs; dst = ch; i4 = gt - NX4; }
  else                     { src = wts;  dst = wb; i4 = gt - (NX4 + NC4); }
  float4 v = ((const float4*)src)[i4];
  ushort4 o;
  o.x = bf16_rne(v.x); o.y = bf16_rne(v.y);
  o.z = bf16_rne(v.z); o.w = bf16_rne(v.w);
  ((ushort4*)dst)[i4] = o;

  if (gt < N_FCNS) {   // fp32-exact half-norms from original ctrs
    const float4* cp4 = (const float4*)(ctrs + (size_t)gt * D_IN);
    float a = 0.f;
    #pragma unroll
    for (int q = 0; q < 8; ++q) {
      float4 c = cp4[q];
      a += c.x * c.x + c.y * c.y + c.z * c.z + c.w * c.w;
    }
    hb[gt] = -0.5f * a;
  }
}

// ---------------- Kernel 1: MEGA -- topk + fp64 refine + gather-apply --------
// R16 verbatim EXCEPT phase 5: W loads widened uint2->uint4 (half the VMEM
// requests, 1 task/thread with 8 cols + 2 accumulators). Per-column FMA order
// identical -> bitwise-identical y.
__global__ __launch_bounds__(256) void k_mega(
    const unsigned short* __restrict__ xh, const unsigned short* __restrict__ ch,
    const float* __restrict__ hb,
    const float* __restrict__ x, const float* __restrict__ ctrs,
    const unsigned short* __restrict__ wb, const float* __restrict__ offs,
    float* __restrict__ y)
{
  // arena: phase1 cand = 4*16*16*4 u32 = 16384 B;
  //        phase4/5 diff = 16*4*33 f32 = 8448 B, part = 16*4*8 f32x4 = 8192 B
  __shared__ __align__(16) char u_mem[16640];
  __shared__ float    s_hb[SPLITS * CPS];                      // 8 KB
  __shared__ unsigned s_pool[SMP][POOL];                       // 3 KB
  __shared__ double   s_pd2[SMP][POOL];                        // 6 KB
  __shared__ int      s_pix[SMP][POOL];                        // 3 KB
  __shared__ int      s_sel[SMP][KNN];                         // 256 B

  unsigned* s_cand = (unsigned*)u_mem;          // [w][row][col][e] flattened
  float*    s_diff = (float*)u_mem;             // [sl][j][33] flattened
  float4*   s_part = (float4*)(u_mem + 8448);   // [sl][j][8] flattened

  const int tid = threadIdx.x;
  const int lane = tid & 63;
  const int w = __builtin_amdgcn_readfirstlane(tid >> 6);  // wave = split
  const int col = lane & 15;
  const int quad = lane >> 4;
  const int sbase = blockIdx.x * SMP;
  const int nbase0 = w * CPS;

  // stage this wave's split hb into LDS (coalesced, once)
  #pragma unroll
  for (int r = 0; r < CPS / 64; ++r)
    s_hb[nbase0 + r * 64 + lane] = hb[nbase0 + r * 64 + lane];

  // ---- Phase 1: MFMA topk (identical key construction to R16) ----
  const bf16x8 ah =
      *(const bf16x8*)(xh + (size_t)(sbase + col) * D_IN + quad * 8);

  unsigned ls[4][4];
  #pragma unroll
  for (int r = 0; r < 4; ++r)
    #pragma unroll
    for (int e = 0; e < 4; ++e) ls[r][e] = 0u;   // real keys always > 0

  const unsigned short* chb =
      ch + (size_t)nbase0 * D_IN + (size_t)col * D_IN + quad * 8;
  #define BLOAD(t) (*(const bf16x8*)(chb + (size_t)(t) * 16 * D_IN))
  #define HLOAD(t) (s_hb[nbase0 + (t) * 16 + col])

  __syncthreads();   // s_hb visible

  bf16x8 bh[4];
  float  hv[4];
  #pragma unroll
  for (int p = 0; p < 4; ++p) { bh[p] = BLOAD(p); hv[p] = HLOAD(p); }

  for (int t = 0; t < TILES; t += 4) {
    #pragma unroll
    for (int p = 0; p < 4; ++p) {
      {
        f32x4 acc = {0.f, 0.f, 0.f, 0.f};
        acc = __builtin_amdgcn_mfma_f32_16x16x32_bf16(ah, bh[p], acc, 0, 0, 0);
        const unsigned tc = (unsigned)((t + p) * 16 + col);
        const float hvv = hv[p];
        #pragma unroll
        for (int r = 0; r < 4; ++r) {
          const float uu = acc[r] + hvv;
          unsigned b = __float_as_uint(uu);
          unsigned m = b ^ ((unsigned)((int)b >> 31) | 0x80000000u);
          unsigned key = (m & 0xFFFFFE00u) | tc;
          unsigned t0 = umin_u(ls[r][0], key); ls[r][0] = umax_u(ls[r][0], key);
          unsigned t1 = umin_u(ls[r][1], t0);  ls[r][1] = umax_u(ls[r][1], t0);
          unsigned t2 = umin_u(ls[r][2], t1);  ls[r][2] = umax_u(ls[r][2], t1);
          ls[r][3] = umax_u(ls[r][3], t2);
        }
      }
      const int tn = (t + 4 + p) & (TILES - 1);
      bh[p] = BLOAD(tn);
      hv[p] = HLOAD(tn);
    }
  }
  #undef BLOAD
  #undef HLOAD

  #pragma unroll
  for (int r = 0; r < 4; ++r) {
    const int row = quad * 4 + r;
    *(uint4*)&s_cand[(((w * 16) + row) * 16 + col) * 4] =
        make_uint4(ls[r][0], ls[r][1], ls[r][2], ls[r][3]);
  }
  __syncthreads();

  // subset top-6 -> s_pool (same mapping as R16)
  if (tid < 128) {
    const int sl = tid >> 3;
    const int g  = tid & 7;
    const int wv = g >> 1;
    const int chh = (g & 1) * 8;
    unsigned q0 = 0, q1 = 0, q2 = 0, q3 = 0, q4 = 0, q5 = 0;
    #pragma unroll
    for (int c2 = 0; c2 < 8; ++c2) {
      uint4 kv = *(const uint4*)&s_cand[(((wv * 16) + sl) * 16 + chh + c2) * 4];
      unsigned ks[4] = {kv.x, kv.y, kv.z, kv.w};
      #pragma unroll
      for (int e = 0; e < 4; ++e) {
        unsigned key = ks[e];
        unsigned t0 = umin_u(q0, key); q0 = umax_u(q0, key);
        unsigned t1 = umin_u(q1, t0);  q1 = umax_u(q1, t0);
        unsigned t2 = umin_u(q2, t1);  q2 = umax_u(q2, t1);
        unsigned t3 = umin_u(q3, t2);  q3 = umax_u(q3, t2);
        unsigned t4 = umin_u(q4, t3);  q4 = umax_u(q4, t3);
        q5 = umax_u(q5, t4);
      }
    }
    unsigned* op = &s_pool[sl][g * 6];
    op[0] = q0; op[1] = q1; op[2] = q2;
    op[3] = q3; op[4] = q4; op[5] = q5;
  }
  __syncthreads();

  // ---- Phase 2: fp64 exact distances for all 16*48 pool entries ----
  for (int c = tid; c < SMP * POOL; c += 256) {
    const int sl = c / POOL;
    const int p = c - sl * POOL;
    const unsigned key = s_pool[sl][p];
    const int wv = p / 12;
    const int j = wv * CPS + (int)(key & 0x1FFu);
    const float4* xp4 = (const float4*)(x + (size_t)(sbase + sl) * D_IN);
    const float4* cp4 = (const float4*)(ctrs + (size_t)j * D_IN);
    double d2a = 0.0, d2b = 0.0;
    #pragma unroll
    for (int q = 0; q < 8; ++q) {
      float4 cv = cp4[q];
      float4 xv = xp4[q];
      double df0 = (double)xv.x - (double)cv.x;
      double df1 = (double)xv.y - (double)cv.y;
      double df2 = (double)xv.z - (double)cv.z;
      double df3 = (double)xv.w - (double)cv.w;
      d2a = fma(df0, df0, d2a);
      d2b = fma(df1, df1, d2b);
      d2a = fma(df2, df2, d2a);
      d2b = fma(df3, df3, d2b);
    }
    s_pd2[sl][p] = d2a + d2b;
    s_pix[sl][p] = j;
  }
  __syncthreads();

  // ---- Phase 3: per-sample fp64 top-4, np tie-break (proven) ----
  if (tid < SMP) {
    double bd[4]; int b4[4];
    #pragma unroll
    for (int e = 0; e < 4; ++e) { bd[e] = 1e300; b4[e] = 0x7fffffff; }
    for (int m = 0; m < POOL; ++m) {
      const double d2 = s_pd2[tid][m];
      const int j = s_pix[tid][m];
      bool ins = (d2 < bd[3]) || (d2 == bd[3] && j < b4[3]);
      if (ins) {
        bd[3] = d2; b4[3] = j;
        #pragma unroll
        for (int q = 3; q > 0; --q) {
          bool sw = (bd[q] < bd[q - 1]) ||
                    (bd[q] == bd[q - 1] && b4[q] < b4[q - 1]);
          if (sw) {
            double td = bd[q]; bd[q] = bd[q - 1]; bd[q - 1] = td;
            int    tj = b4[q]; b4[q] = b4[q - 1]; b4[q - 1] = tj;
          }
        }
      }
    }
    #pragma unroll
    for (int q = 0; q < 4; ++q) s_sel[tid][q] = b4[q];
  }
  __syncthreads();   // s_cand region dead from here; reuse as diff/part

  // ---- Phase 4: diff staging (overlays dead cand region) ----
  #pragma unroll
  for (int r = 0; r < SMP * KNN * D_IN / 256; ++r) {
    int v = r * 256 + tid;
    int d = v & 31; int p = v >> 5;
    int sl = p >> 2; int j = p & 3;
    int f = s_sel[sl][j];
    s_diff[(sl * KNN + j) * (D_IN + 1) + d] =
        x[(size_t)(sbase + sl) * D_IN + d] - ctrs[(size_t)f * D_IN + d];
  }
  __syncthreads();

  // ---- Phase 5: bf16-W gather-apply, uint4 W loads, 1 task/thread ----
  // task: sl = tid>>4, j = (tid>>2)&3, eq8 = tid&3 (8 cols = eq 2*eq8,2*eq8+1)
  {
    const int sl  = tid >> 4;
    const int j   = (tid >> 2) & 3;
    const int eq8 = tid & 3;
    const int f = s_sel[sl][j];
    const uint4* wp = (const uint4*)(wb + (size_t)f * (D_IN * D_OUT));
    const float4* op4 = (const float4*)(offs + (size_t)f * D_OUT);
    float4 acc0 = op4[2 * eq8];       // cols [8*eq8,   8*eq8+4)
    float4 acc1 = op4[2 * eq8 + 1];   // cols [8*eq8+4, 8*eq8+8)
    #pragma unroll
    for (int d = 0; d < D_IN; ++d) {
      uint4 wv = wp[d * 4 + eq8];     // 8 bf16 cols, one 16 B load
      float w0 = __uint_as_float(wv.x << 16);
      float w1 = __uint_as_float(wv.x & 0xFFFF0000u);
      float w2 = __uint_as_float(wv.y << 16);
      float w3 = __uint_as_float(wv.y & 0xFFFF0000u);
      float w4 = __uint_as_float(wv.z << 16);
      float w5 = __uint_as_float(wv.z & 0xFFFF0000u);
      float w6 = __uint_as_float(wv.w << 16);
      float w7 = __uint_as_float(wv.w & 0xFFFF0000u);
      float xc = s_diff[(sl * KNN + j) * (D_IN + 1) + d];
      acc0.x = fmaf(xc, w0, acc0.x);
      acc0.y = fmaf(xc, w1, acc0.y);
      acc0.z = fmaf(xc, w2, acc0.z);
      acc0.w = fmaf(xc, w3, acc0.w);
      acc1.x = fmaf(xc, w4, acc1.x);
      acc1.y = fmaf(xc, w5, acc1.y);
      acc1.z = fmaf(xc, w6, acc1.z);
      acc1.w = fmaf(xc, w7, acc1.w);
    }
    s_part[(sl * KNN + j) * 8 + 2 * eq8] = acc0;
    s_part[(sl * KNN + j) * 8 + 2 * eq8 + 1] = acc1;
  }
  __syncthreads();

  #pragma unroll
  for (int r = 0; r < 2; ++r) {
    const int slot = r * 256 + tid;
    const int sl = slot >> 5;
    const int j  = (slot >> 3) & 3;
    const int eq = slot & 7;
    if (j == 0) {
      float4 a = s_part[(sl * KNN + 0) * 8 + eq];
      float4 b = s_part[(sl * KNN + 1) * 8 + eq];
      float4 c = s_part[(sl * KNN + 2) * 8 + eq];
      float4 e = s_part[(sl * KNN + 3) * 8 + eq];
      float4 o;
      o.x = (a.x + b.x) + (c.x + e.x);
      o.y = (a.y + b.y) + (c.y + e.y);
      o.z = (a.z + b.z) + (c.z + e.z);
      o.w = (a.w + b.w) + (c.w + e.w);
      ((float4*)(y + (size_t)(sbase + sl) * D_OUT))[eq] = o;
    }
  }
}

// ---------------- launch: 2 dispatches ---------------------------------------
extern "C" void kernel_launch(void* const* d_in, const int* in_sizes, int n_in,
                              void* d_out, int out_size, void* d_ws, size_t ws_size,
                              hipStream_t stream) {
  const float* x    = (const float*)d_in[0];
  const float* ctrs = (const float*)d_in[1];
  const float* wts  = (const float*)d_in[2];
  const float* offs = (const float*)d_in[3];
  float* y = (float*)d_out;

  char* ws = (char*)d_ws;
  unsigned short* xh = (unsigned short*)(ws + OFF_XH);
  unsigned short* ch = (unsigned short*)(ws + OFF_CH);
  float*          hb = (float*)(ws + OFF_HB);
  unsigned short* wb = (unsigned short*)(ws + OFF_WB);

  k_prep<<<NTOT / 256, 256, 0, stream>>>(x, ctrs, wts, xh, ch, wb, hb);
  k_mega<<<N_SMPS / SMP, 256, 0, stream>>>(xh, ch, hb, x, ctrs, wb, offs, y);
}